// Round 8
// baseline (60.635 us; speedup 1.0000x reference)
//
#include <hip/hip_runtime.h>

typedef float f32x4 __attribute__((ext_vector_type(4)));
typedef _Float16 f16x8 __attribute__((ext_vector_type(8)));
typedef __fp16 fp16x2 __attribute__((ext_vector_type(2)));

#define NEG_SLOPE 0.2f
#define MASK_EPS 1e-8f

// ---------------------------------------------------------------------------
// Kernel 0 (tiny): W (f32 [k][n]) -> wTf16 (f16 [n][k]). 16384 elements.
// ---------------------------------------------------------------------------
__global__ __launch_bounds__(256) void gat_prep_w(
    const float* __restrict__ W, _Float16* __restrict__ wTf16) {
  const int idx = blockIdx.x * 256 + threadIdx.x;
  const int k = idx >> 7, n = idx & 127;
  wTf16[n * 128 + k] = (_Float16)W[idx];
}

// ---------------------------------------------------------------------------
// Kernel 1: Wh = h @ W via f16 MFMA. Zero LDS, zero barriers.
// Block = 16 rows; 4 waves = 4 heads (n-quarters of 32 cols).
// A-frag: h f32 direct loads + cvt_pkrtz; B-frag: wTf16 16B loads (L1/L2-hot).
// Epilogue: per-head scores s_i/s_j from f32 acc (shuffle-reduce over nl),
// whT written as packed f16.
// ---------------------------------------------------------------------------
__global__ __launch_bounds__(256, 4) void gat_wh_mfma(
    const float* __restrict__ h, const _Float16* __restrict__ wTf16,
    const float* __restrict__ a, _Float16* __restrict__ whT,
    float* __restrict__ sIT, float* __restrict__ sJT) {
  const int tid = threadIdx.x;
  const int bid = blockIdx.x;          // 0..1023, 16 rows each
  const int w = tid >> 6;              // wave = head
  const int lane = tid & 63;
  const int nl = lane & 15;
  const int ig = lane >> 4;
  const int row0 = bid * 16;
  const int bb = row0 >> 9;
  const int iloc = row0 & 511;

  const float* hP = h + (size_t)(row0 + nl) * 128 + ig * 8;
  const _Float16* wP0 = wTf16 + (size_t)(w * 32 + nl) * 128 + ig * 8;
  const _Float16* wP1 = wTf16 + (size_t)(w * 32 + 16 + nl) * 128 + ig * 8;

  f32x4 acc0 = {0.f, 0.f, 0.f, 0.f};
  f32x4 acc1 = {0.f, 0.f, 0.f, 0.f};

#pragma unroll
  for (int kt = 0; kt < 4; ++kt) {
    f32x4 ha = *(const f32x4*)(hP + kt * 32);
    f32x4 hb = *(const f32x4*)(hP + kt * 32 + 4);
    union { fp16x2 h2[4]; f16x8 v; } af;
    af.h2[0] = __builtin_amdgcn_cvt_pkrtz(ha.x, ha.y);
    af.h2[1] = __builtin_amdgcn_cvt_pkrtz(ha.z, ha.w);
    af.h2[2] = __builtin_amdgcn_cvt_pkrtz(hb.x, hb.y);
    af.h2[3] = __builtin_amdgcn_cvt_pkrtz(hb.z, hb.w);
    const f16x8 b0 = *(const f16x8*)(wP0 + kt * 32);
    const f16x8 b1 = *(const f16x8*)(wP1 + kt * 32);
    acc0 = __builtin_amdgcn_mfma_f32_16x16x32_f16(af.v, b0, acc0, 0, 0, 0);
    acc1 = __builtin_amdgcn_mfma_f32_16x16x32_f16(af.v, b1, acc1, 0, 0, 0);
  }

  // ---- per-head scores (full fp32 path) ----
  const float avS0 = a[w * 64 + nl];
  const float avS1 = a[w * 64 + 16 + nl];
  const float avD0 = a[w * 64 + 32 + nl];
  const float avD1 = a[w * 64 + 48 + nl];

  float si[4], sj[4];
#pragma unroll
  for (int reg = 0; reg < 4; ++reg) {
    si[reg] = acc0[reg] * avS0 + acc1[reg] * avS1;
    sj[reg] = acc0[reg] * avD0 + acc1[reg] * avD1;
#pragma unroll
    for (int off = 1; off < 16; off <<= 1) {
      si[reg] += __shfl_xor(si[reg], off, 64);
      sj[reg] += __shfl_xor(sj[reg], off, 64);
    }
  }
  if (nl == 0) {
    const int base = bb * 2048 + w * 512 + iloc + ig * 4;
#pragma unroll
    for (int reg = 0; reg < 4; ++reg) {
      sIT[base + reg] = si[reg];
      sJT[base + reg] = sj[reg];
    }
  }

  // ---- whT f16 writes (C layout: row m = ig*4+reg -> i, col n = nl -> d) ----
  union { fp16x2 h2[2]; float2 f2; } p0, p1;
  p0.h2[0] = __builtin_amdgcn_cvt_pkrtz(acc0[0], acc0[1]);
  p0.h2[1] = __builtin_amdgcn_cvt_pkrtz(acc0[2], acc0[3]);
  p1.h2[0] = __builtin_amdgcn_cvt_pkrtz(acc1[0], acc1[1]);
  p1.h2[1] = __builtin_amdgcn_cvt_pkrtz(acc1[2], acc1[3]);
  _Float16* wout = whT + (size_t)bb * 128 * 512 + iloc + ig * 4;
  *(float2*)(wout + (size_t)(w * 32 + nl) * 512)      = p0.f2;
  *(float2*)(wout + (size_t)(w * 32 + 16 + nl) * 512) = p1.f2;
}

// ---------------------------------------------------------------------------
// Kernel 2: attention+aggregate. Zero LDS, zero barriers. adj consumed
// directly (register double-buffered, 16 scalar loads/tile in flight);
// si/WhT fragments direct from L2; exp/mask fp32; MFMA 16x16x32 f16.
// Grid (jt, b) so consecutive blocks share one b's whT/sIT (L2 locality).
// ---------------------------------------------------------------------------
__global__ __launch_bounds__(256, 4) void gat_attn_kernel(
    const float* __restrict__ adj, const _Float16* __restrict__ whT,
    const float* __restrict__ sIT, const float* __restrict__ sJT,
    float* __restrict__ out) {
  const int tid = threadIdx.x;
  const int b = blockIdx.y;            // 0..31
  const int j0 = blockIdx.x * 16;      // 32 tiles
  const int wv = tid >> 6;             // wave = head
  const int lane = tid & 63;
  const int nl = lane & 15;
  const int ig = lane >> 4;

  const float sj = sJT[b * 2048 + wv * 512 + j0 + nl];

  const float* adjP = adj + (size_t)b * 512 * 512 + (size_t)(ig * 8) * 512 + j0 + nl;
  const _Float16* whP = whT + (size_t)b * 128 * 512 + (size_t)(wv * 32 + nl) * 512 + ig * 8;
  const float* siP = sIT + b * 2048 + wv * 512 + ig * 8;

  f32x4 acc0 = {0.f, 0.f, 0.f, 0.f};
  f32x4 acc1 = {0.f, 0.f, 0.f, 0.f};
  float l = 0.f;

  float adjReg[2][16];                 // [buf][ks*8 + r]

  // prologue: tile-0 adj
#pragma unroll
  for (int ks = 0; ks < 2; ++ks)
#pragma unroll
    for (int r = 0; r < 8; ++r)
      adjReg[0][ks * 8 + r] = adjP[(size_t)(ks * 32 + r) * 512];

#pragma unroll
  for (int t = 0; t < 8; ++t) {
    const int cur = t & 1;
    if (t < 7) {                       // prefetch next tile's adj
#pragma unroll
      for (int ks = 0; ks < 2; ++ks)
#pragma unroll
        for (int r = 0; r < 8; ++r)
          adjReg[cur ^ 1][ks * 8 + r] =
              adjP[(size_t)((t + 1) * 64 + ks * 32 + r) * 512];
    }

#pragma unroll
    for (int ks = 0; ks < 2; ++ks) {
      f32x4 sA = *(const f32x4*)(siP + t * 64 + ks * 32);
      f32x4 sB = *(const f32x4*)(siP + t * 64 + ks * 32 + 4);
      const f16x8 bf0 = *(const f16x8*)(whP + t * 64 + ks * 32);
      const f16x8 bf1 = *(const f16x8*)(whP + 16 * 512 + t * 64 + ks * 32);

      float si[8] = {sA.x, sA.y, sA.z, sA.w, sB.x, sB.y, sB.z, sB.w};
      float p[8];
#pragma unroll
      for (int r = 0; r < 8; ++r) {
        float e = si[r] + sj;
        e = e >= 0.f ? e : NEG_SLOPE * e;
        float av = adjReg[cur][ks * 8 + r];
        p[r] = av > MASK_EPS ? __expf(e) : 0.f;
      }
      l += ((p[0] + p[1]) + (p[2] + p[3])) + ((p[4] + p[5]) + (p[6] + p[7]));

      union { fp16x2 h2[4]; f16x8 v; } af;
#pragma unroll
      for (int q = 0; q < 4; ++q)
        af.h2[q] = __builtin_amdgcn_cvt_pkrtz(p[2 * q], p[2 * q + 1]);

      acc0 = __builtin_amdgcn_mfma_f32_16x16x32_f16(af.v, bf0, acc0, 0, 0, 0);
      acc1 = __builtin_amdgcn_mfma_f32_16x16x32_f16(af.v, bf1, acc1, 0, 0, 0);
    }
  }

  // reduce l over the 4 ig-slices -> every lane has l for j = j0 + nl
  l += __shfl_xor(l, 16, 64);
  l += __shfl_xor(l, 32, 64);

  // D layout: row(m=j_local) = 4*ig + reg, col(n=d_lo) = nl
  float* outB = out + ((size_t)b * 512 + j0) * 128 + wv * 32;
#pragma unroll
  for (int reg = 0; reg < 4; ++reg) {
    const int jr = 4 * ig + reg;
    const float rl = 1.0f / __shfl(l, jr, 64);
    outB[(size_t)jr * 128 + nl]      = acc0[reg] * rl;
    outB[(size_t)jr * 128 + 16 + nl] = acc1[reg] * rl;
  }
}

extern "C" void kernel_launch(void* const* d_in, const int* in_sizes, int n_in,
                              void* d_out, int out_size, void* d_ws, size_t ws_size,
                              hipStream_t stream) {
  const float* h = (const float*)d_in[0];     // (32, 512, 128)
  const float* adj = (const float*)d_in[1];   // (32, 512, 512)
  const float* W = (const float*)d_in[2];     // (128, 128)
  const float* a = (const float*)d_in[3];     // (4, 64)
  float* out = (float*)d_out;                 // (32, 512, 128)

  _Float16* whT = (_Float16*)d_ws;                      // 4 MB
  float* sIT = (float*)(whT + (size_t)32 * 128 * 512);  // 256 KB
  float* sJT = sIT + (size_t)32 * 4 * 512;              // 256 KB
  _Float16* wTf16 = (_Float16*)(sJT + (size_t)32 * 4 * 512);  // 32 KB

  gat_prep_w<<<dim3(64), dim3(256), 0, stream>>>(W, wTf16);
  gat_wh_mfma<<<dim3(1024), dim3(256), 0, stream>>>(h, wTf16, a, whT, sIT, sJT);
  gat_attn_kernel<<<dim3(32, 32), dim3(256), 0, stream>>>(adj, whT, sIT, sJT, out);
}

// Round 9
// 55.999 us; speedup vs baseline: 1.0828x; 1.0828x over previous
//
#include <hip/hip_runtime.h>

typedef float f32x4 __attribute__((ext_vector_type(4)));
typedef _Float16 f16x8 __attribute__((ext_vector_type(8)));
typedef __fp16 fp16x2 __attribute__((ext_vector_type(2)));

#define NEG_SLOPE 0.2f
#define MASK_EPS 1e-8f

// ---------------------------------------------------------------------------
// Kernel 0 (tiny): W (f32 [k][n]) -> wTf16 (f16 [n][k]). 16384 elements.
// ---------------------------------------------------------------------------
__global__ __launch_bounds__(256) void gat_prep_w(
    const float* __restrict__ W, _Float16* __restrict__ wTf16) {
  const int idx = blockIdx.x * 256 + threadIdx.x;
  const int k = idx >> 7, n = idx & 127;
  wTf16[n * 128 + k] = (_Float16)W[idx];
}

// ---------------------------------------------------------------------------
// Kernel 1: Wh = h @ W via f16 MFMA. Zero LDS, zero barriers.
// Block = 16 rows; 4 waves = 4 heads (n-quarters of 32 cols).
// ---------------------------------------------------------------------------
__global__ __launch_bounds__(256, 4) void gat_wh_mfma(
    const float* __restrict__ h, const _Float16* __restrict__ wTf16,
    const float* __restrict__ a, _Float16* __restrict__ whT,
    float* __restrict__ sIT, float* __restrict__ sJT) {
  const int tid = threadIdx.x;
  const int bid = blockIdx.x;          // 0..1023, 16 rows each
  const int w = tid >> 6;              // wave = head
  const int lane = tid & 63;
  const int nl = lane & 15;
  const int ig = lane >> 4;
  const int row0 = bid * 16;
  const int bb = row0 >> 9;
  const int iloc = row0 & 511;

  const float* hP = h + (size_t)(row0 + nl) * 128 + ig * 8;
  const _Float16* wP0 = wTf16 + (size_t)(w * 32 + nl) * 128 + ig * 8;
  const _Float16* wP1 = wTf16 + (size_t)(w * 32 + 16 + nl) * 128 + ig * 8;

  f32x4 acc0 = {0.f, 0.f, 0.f, 0.f};
  f32x4 acc1 = {0.f, 0.f, 0.f, 0.f};

#pragma unroll
  for (int kt = 0; kt < 4; ++kt) {
    f32x4 ha = *(const f32x4*)(hP + kt * 32);
    f32x4 hb = *(const f32x4*)(hP + kt * 32 + 4);
    union { fp16x2 h2[4]; f16x8 v; } af;
    af.h2[0] = __builtin_amdgcn_cvt_pkrtz(ha.x, ha.y);
    af.h2[1] = __builtin_amdgcn_cvt_pkrtz(ha.z, ha.w);
    af.h2[2] = __builtin_amdgcn_cvt_pkrtz(hb.x, hb.y);
    af.h2[3] = __builtin_amdgcn_cvt_pkrtz(hb.z, hb.w);
    const f16x8 b0 = *(const f16x8*)(wP0 + kt * 32);
    const f16x8 b1 = *(const f16x8*)(wP1 + kt * 32);
    acc0 = __builtin_amdgcn_mfma_f32_16x16x32_f16(af.v, b0, acc0, 0, 0, 0);
    acc1 = __builtin_amdgcn_mfma_f32_16x16x32_f16(af.v, b1, acc1, 0, 0, 0);
  }

  // ---- per-head scores (full fp32 path) ----
  const float avS0 = a[w * 64 + nl];
  const float avS1 = a[w * 64 + 16 + nl];
  const float avD0 = a[w * 64 + 32 + nl];
  const float avD1 = a[w * 64 + 48 + nl];

  float si[4], sj[4];
#pragma unroll
  for (int reg = 0; reg < 4; ++reg) {
    si[reg] = acc0[reg] * avS0 + acc1[reg] * avS1;
    sj[reg] = acc0[reg] * avD0 + acc1[reg] * avD1;
#pragma unroll
    for (int off = 1; off < 16; off <<= 1) {
      si[reg] += __shfl_xor(si[reg], off, 64);
      sj[reg] += __shfl_xor(sj[reg], off, 64);
    }
  }
  if (nl == 0) {
    const int base = bb * 2048 + w * 512 + iloc + ig * 4;
#pragma unroll
    for (int reg = 0; reg < 4; ++reg) {
      sIT[base + reg] = si[reg];
      sJT[base + reg] = sj[reg];
    }
  }

  // ---- whT f16 writes ----
  union { fp16x2 h2[2]; float2 f2; } p0, p1;
  p0.h2[0] = __builtin_amdgcn_cvt_pkrtz(acc0[0], acc0[1]);
  p0.h2[1] = __builtin_amdgcn_cvt_pkrtz(acc0[2], acc0[3]);
  p1.h2[0] = __builtin_amdgcn_cvt_pkrtz(acc1[0], acc1[1]);
  p1.h2[1] = __builtin_amdgcn_cvt_pkrtz(acc1[2], acc1[3]);
  _Float16* wout = whT + (size_t)bb * 128 * 512 + iloc + ig * 4;
  *(float2*)(wout + (size_t)(w * 32 + nl) * 512)      = p0.f2;
  *(float2*)(wout + (size_t)(w * 32 + 16 + nl) * 512) = p1.f2;
}

// ---------------------------------------------------------------------------
// Kernel 2: attention+aggregate. Zero LDS, zero barriers. adj direct from
// global, register prefetch DEPTH 2 (32 outstanding scalar loads). Grid
// (b=x, jt=y): jt-neighbors (sharing 128B adj lines) are 32 blocks apart
// = same XCD (32%8==0) -> shared line halves hit L2, not HBM.
// ---------------------------------------------------------------------------
__global__ __launch_bounds__(256, 4) void gat_attn_kernel(
    const float* __restrict__ adj, const _Float16* __restrict__ whT,
    const float* __restrict__ sIT, const float* __restrict__ sJT,
    float* __restrict__ out) {
  const int tid = threadIdx.x;
  const int b = blockIdx.x;            // 0..31 (fast-varying)
  const int j0 = blockIdx.y * 16;      // 32 tiles
  const int wv = tid >> 6;             // wave = head
  const int lane = tid & 63;
  const int nl = lane & 15;
  const int ig = lane >> 4;

  const float sj = sJT[b * 2048 + wv * 512 + j0 + nl];

  const float* adjP = adj + (size_t)b * 512 * 512 + (size_t)(ig * 8) * 512 + j0 + nl;
  const _Float16* whP = whT + (size_t)b * 128 * 512 + (size_t)(wv * 32 + nl) * 512 + ig * 8;
  const float* siP = sIT + b * 2048 + wv * 512 + ig * 8;

  f32x4 acc0 = {0.f, 0.f, 0.f, 0.f};
  f32x4 acc1 = {0.f, 0.f, 0.f, 0.f};
  float l = 0.f;

  float adjReg[3][16];                 // depth-2 prefetch ring

  // prologue: tiles 0 and 1
#pragma unroll
  for (int pt = 0; pt < 2; ++pt)
#pragma unroll
    for (int ks = 0; ks < 2; ++ks)
#pragma unroll
      for (int r = 0; r < 8; ++r)
        adjReg[pt][ks * 8 + r] = adjP[(size_t)(pt * 64 + ks * 32 + r) * 512];

#pragma unroll
  for (int t = 0; t < 8; ++t) {
    const int cur = t % 3;
    if (t < 6) {                       // prefetch tile t+2
      const int nxt = (t + 2) % 3;
#pragma unroll
      for (int ks = 0; ks < 2; ++ks)
#pragma unroll
        for (int r = 0; r < 8; ++r)
          adjReg[nxt][ks * 8 + r] =
              adjP[(size_t)((t + 2) * 64 + ks * 32 + r) * 512];
    }

#pragma unroll
    for (int ks = 0; ks < 2; ++ks) {
      f32x4 sA = *(const f32x4*)(siP + t * 64 + ks * 32);
      f32x4 sB = *(const f32x4*)(siP + t * 64 + ks * 32 + 4);
      const f16x8 bf0 = *(const f16x8*)(whP + t * 64 + ks * 32);
      const f16x8 bf1 = *(const f16x8*)(whP + 16 * 512 + t * 64 + ks * 32);

      float si[8] = {sA.x, sA.y, sA.z, sA.w, sB.x, sB.y, sB.z, sB.w};
      float p[8];
#pragma unroll
      for (int r = 0; r < 8; ++r) {
        float e = si[r] + sj;
        e = e >= 0.f ? e : NEG_SLOPE * e;
        float av = adjReg[cur][ks * 8 + r];
        p[r] = av > MASK_EPS ? __expf(e) : 0.f;
      }
      l += ((p[0] + p[1]) + (p[2] + p[3])) + ((p[4] + p[5]) + (p[6] + p[7]));

      union { fp16x2 h2[4]; f16x8 v; } af;
#pragma unroll
      for (int q = 0; q < 4; ++q)
        af.h2[q] = __builtin_amdgcn_cvt_pkrtz(p[2 * q], p[2 * q + 1]);

      acc0 = __builtin_amdgcn_mfma_f32_16x16x32_f16(af.v, bf0, acc0, 0, 0, 0);
      acc1 = __builtin_amdgcn_mfma_f32_16x16x32_f16(af.v, bf1, acc1, 0, 0, 0);
    }
  }

  // reduce l over the 4 ig-slices -> every lane has l for j = j0 + nl
  l += __shfl_xor(l, 16, 64);
  l += __shfl_xor(l, 32, 64);

  // D layout: row(m=j_local) = 4*ig + reg, col(n=d_lo) = nl
  float* outB = out + ((size_t)b * 512 + j0) * 128 + wv * 32;
#pragma unroll
  for (int reg = 0; reg < 4; ++reg) {
    const int jr = 4 * ig + reg;
    const float rl = 1.0f / __shfl(l, jr, 64);
    outB[(size_t)jr * 128 + nl]      = acc0[reg] * rl;
    outB[(size_t)jr * 128 + 16 + nl] = acc1[reg] * rl;
  }
}

extern "C" void kernel_launch(void* const* d_in, const int* in_sizes, int n_in,
                              void* d_out, int out_size, void* d_ws, size_t ws_size,
                              hipStream_t stream) {
  const float* h = (const float*)d_in[0];     // (32, 512, 128)
  const float* adj = (const float*)d_in[1];   // (32, 512, 512)
  const float* W = (const float*)d_in[2];     // (128, 128)
  const float* a = (const float*)d_in[3];     // (4, 64)
  float* out = (float*)d_out;                 // (32, 512, 128)

  _Float16* whT = (_Float16*)d_ws;                      // 4 MB
  float* sIT = (float*)(whT + (size_t)32 * 128 * 512);  // 256 KB
  float* sJT = sIT + (size_t)32 * 4 * 512;              // 256 KB
  _Float16* wTf16 = (_Float16*)(sJT + (size_t)32 * 4 * 512);  // 32 KB

  gat_prep_w<<<dim3(64), dim3(256), 0, stream>>>(W, wTf16);
  gat_wh_mfma<<<dim3(1024), dim3(256), 0, stream>>>(h, wTf16, a, whT, sIT, sJT);
  gat_attn_kernel<<<dim3(32, 32), dim3(256), 0, stream>>>(adj, whT, sIT, sJT, out);
}